// Round 4
// baseline (111.172 us; speedup 1.0000x reference)
//
#include <hip/hip_runtime.h>
#include <stdint.h>

constexpr int Bn = 8, Cn = 64, Hn = 128, Wn = 128;
constexpr int HsC = 64, WsC = 64;
constexpr int Kn = 256;                 // C * r^2
constexpr int PX = HsC * WsC;           // 4096 pixels per (t,b) plane
constexpr float DECAYF = 0.25f;

typedef __attribute__((ext_vector_type(8))) short short8v;
typedef __attribute__((ext_vector_type(4))) float f32x4;

static __device__ __forceinline__ ushort f2bf_rn(float f) {
    uint32_t u = __float_as_uint(f);
    uint32_t r = (u + 0x7FFFu + ((u >> 16) & 1u)) >> 16;
    return (ushort)r;
}
static __device__ __forceinline__ float bf2f(ushort u) {
    return __uint_as_float(((uint32_t)u) << 16);
}

// u8 spikes (0..4) -> 8 bf16 via v_perm byte-LUT (exact). Verified.
static __device__ __forceinline__ short8v unpack8(uint32_t s0, uint32_t s1) {
    uint32_t lo0 = __builtin_amdgcn_perm(0x00000080u, 0x40008000u, s0);
    uint32_t hi0 = __builtin_amdgcn_perm(0x00000040u, 0x40403F00u, s0);
    uint32_t lo1 = __builtin_amdgcn_perm(0x00000080u, 0x40008000u, s1);
    uint32_t hi1 = __builtin_amdgcn_perm(0x00000040u, 0x40403F00u, s1);
    union { uint32_t u[4]; short8v s; } r;
    r.u[0] = __builtin_amdgcn_perm(hi0, lo0, 0x05010400u);
    r.u[1] = __builtin_amdgcn_perm(hi0, lo0, 0x07030602u);
    r.u[2] = __builtin_amdgcn_perm(hi1, lo1, 0x05010400u);
    r.u[3] = __builtin_amdgcn_perm(hi1, lo1, 0x07030602u);
    return r.s;
}

// ---------------------------------------------------------------------------
// Kernel 0: weight prep — fold /4 dequant, split into bf16 hi + lo
// ---------------------------------------------------------------------------
__global__ __launch_bounds__(256) void wprep_kernel(const float* __restrict__ w,
                                                    ushort* __restrict__ wh,
                                                    ushort* __restrict__ wl) {
    int i = blockIdx.x * 256 + threadIdx.x;     // 16384 total
    float wq = w[i] * 0.25f;
    ushort h = f2bf_rn(wq);
    float hf = bf2f(h);
    wh[i] = h;
    wl[i] = f2bf_rn(wq - hf);
}

// ---------------------------------------------------------------------------
// Fused LIF + 1x1 conv (low res; conv commutes with bilinear upsample).
// Block = 512 threads, owns (b, hs row, ws half): 32 px x 64 input c.
// Round-4 restructure: ALL x loaded up front (32 dwordx2 in flight -> HBM-bound),
// all 16 LIF steps register-resident, 4 spike panels in LDS, ONE drain barrier,
// then 4 MFMA phases (y_lds double-buffered, 1 barrier each). 5 barriers total.
// ---------------------------------------------------------------------------
__global__ __launch_bounds__(512) void fused_lif_conv(const float* __restrict__ x,
                                                      const ushort* __restrict__ wh,
                                                      const ushort* __restrict__ wl,
                                                      ushort* __restrict__ y) {
    __shared__ __align__(16) uint8_t sp_lds[4][32 * 256];   // 32 KB
    __shared__ __align__(8)  uint8_t y_lds[2][32 * 128];    // 8 KB

    const int tid  = threadIdx.x;
    const int pxl  = tid & 31;          // local pixel (ws within half)
    const int cg   = tid >> 5;          // 0..15, channels cg*4..cg*4+3
    const int lane = tid & 63;
    const int wid  = tid >> 6;          // 0..7
    const int l15  = lane & 15;
    const int g    = lane >> 4;
    const int wc   = wid & 3;           // c_out tile (16 c)
    const int wp   = wid >> 2;          // px tile (16 px)

    const int bid  = blockIdx.x;        // 1024 = 8 b x 64 hs x 2 half
    const int half = bid & 1;
    const int hs   = (bid >> 1) & 63;
    const int b    = bid >> 7;

    const int ws_abs = half * 32 + pxl;
    const int c0 = cg * 4;

    const size_t tstr = (size_t)Bn * Cn * Hn * Wn;
    const float* xb = x + ((size_t)b * Cn + c0) * (Hn * Wn) + (2 * hs) * Wn + 2 * ws_abs;

    // ---- load ALL x for this thread's site: 32 independent dwordx2 ----
    float2 xr0[4][4], xr1[4][4];        // [t][ci]
    #pragma unroll
    for (int t = 0; t < 4; ++t) {
        #pragma unroll
        for (int ci = 0; ci < 4; ++ci) {
            const float* xp = xb + (size_t)t * tstr + ci * (Hn * Wn);
            xr0[t][ci] = *(const float2*)xp;
            xr1[t][ci] = *(const float2*)(xp + Wn);
        }
    }

    // ---- LIF: 16 sequential steps, fully register-resident ----
    uint32_t pk[4][4];                  // [t][ci]
    #pragma unroll
    for (int ci = 0; ci < 4; ++ci) {
        float m = 0.f, s = 0.f, sv;
        #pragma unroll
        for (int t = 0; t < 4; ++t) {
            uint32_t p;
            m = (m - s) * DECAYF + xr0[t][ci].x;
            sv = rintf(fminf(fmaxf(m, 0.f), 4.f)); s = sv * 0.25f; p = (uint32_t)(int)sv;
            m = (m - s) * DECAYF + xr0[t][ci].y;
            sv = rintf(fminf(fmaxf(m, 0.f), 4.f)); s = sv * 0.25f; p |= ((uint32_t)(int)sv) << 8;
            m = (m - s) * DECAYF + xr1[t][ci].x;
            sv = rintf(fminf(fmaxf(m, 0.f), 4.f)); s = sv * 0.25f; p |= ((uint32_t)(int)sv) << 16;
            m = (m - s) * DECAYF + xr1[t][ci].y;
            sv = rintf(fminf(fmaxf(m, 0.f), 4.f)); s = sv * 0.25f; p |= ((uint32_t)(int)sv) << 24;
            pk[t][ci] = p;
        }
    }

    // ---- all 4 spike panels -> LDS (swizzled, 16B granule), one barrier ----
    const int spw = pxl * 256 + ((cg * 16) ^ ((pxl & 15) << 4));
    #pragma unroll
    for (int t = 0; t < 4; ++t)
        *(uint4*)(sp_lds[t] + spw) = make_uint4(pk[t][0], pk[t][1], pk[t][2], pk[t][3]);
    __syncthreads();

    // ---- per-t MFMA + staged writeout ----
    const int bpx  = wp * 16 + l15;                                 // MFMA B pixel
    const int arow = wc * 16 + l15;                                 // MFMA A row (c_out)
    const ushort* whp = wh + arow * Kn;
    const ushort* wlp = wl + arow * Kn;
    const int cb   = wc * 4 + g;                                    // c_out quad idx
    const int ywb  = bpx * 128 + ((cb * 8) ^ ((bpx & 7) << 3));     // y_lds write addr
    const int crow = tid >> 3;          // writeout: c row 0..63
    const int pq   = tid & 7;           // writeout: px quad 0..7

    #pragma unroll
    for (int t = 0; t < 4; ++t) {
        f32x4 acc = {0.f, 0.f, 0.f, 0.f};
        #pragma unroll
        for (int ks = 0; ks < 8; ++ks) {
            int k0 = ks * 32 + g * 8;
            short8v ah = *(const short8v*)(whp + k0);
            short8v al = *(const short8v*)(wlp + k0);
            int rb = bpx * 256 + (k0 ^ ((bpx & 15) << 4));
            uint2 sv2 = *(const uint2*)(sp_lds[t] + rb);
            short8v bf = unpack8(sv2.x, sv2.y);
            acc = __builtin_amdgcn_mfma_f32_16x16x32_bf16(ah, bf, acc, 0, 0, 0);
            acc = __builtin_amdgcn_mfma_f32_16x16x32_bf16(al, bf, acc, 0, 0, 0);
        }

        // epilogue: acc -> y_lds[t&1] [px][c]  (C/D: col=l15=px, row=g*4+r=c)
        uint32_t lo = (uint32_t)f2bf_rn(acc[0]) | ((uint32_t)f2bf_rn(acc[1]) << 16);
        uint32_t hi = (uint32_t)f2bf_rn(acc[2]) | ((uint32_t)f2bf_rn(acc[3]) << 16);
        *(uint2*)(y_lds[t & 1] + ywb) = make_uint2(lo, hi);
        __syncthreads();

        // coalesced y writeout: thread = (crow, pq) -> 4 px bf16
        ushort v[4];
        #pragma unroll
        for (int j = 0; j < 4; ++j) {
            int pxj = pq * 4 + j;
            int addr = pxj * 128 + (((crow >> 2) * 8) ^ ((pxj & 7) << 3)) + (crow & 3) * 2;
            v[j] = *(const ushort*)(y_lds[t & 1] + addr);
        }
        uint2 o = make_uint2((uint32_t)v[0] | ((uint32_t)v[1] << 16),
                             (uint32_t)v[2] | ((uint32_t)v[3] << 16));
        ushort* yg = y + ((size_t)(t * Bn + b) * Cn + crow) * PX + hs * 64 + half * 32 + pq * 4;
        *(uint2*)yg = o;
        // no trailing barrier: y_lds is double-buffered (t+2 write is ordered
        // after the t+1 barrier, which is after all t reads)
    }
}

// ---------------------------------------------------------------------------
// Kernel 3: bilinear 2x upsample from bf16 y, half-pixel centers, edge clamp
// ---------------------------------------------------------------------------
__global__ __launch_bounds__(256) void upsample_kernel(const ushort* __restrict__ y,
                                                       float* __restrict__ out) {
    int gg = blockIdx.x * 256 + threadIdx.x;   // 8388608 threads
    int wq = gg & 31;                // output col quad: w0 = 4*wq
    int h  = (gg >> 5) & 127;
    int rr = gg >> 12;
    int c  = rr & 63;
    int tb = rr >> 6;

    const ushort* yp = y + ((size_t)tb * Cn + c) * PX;

    int m = h >> 1;
    int r0, r1; float v0, v1;
    if ((h & 1) == 0) { r0 = (m - 1 < 0) ? 0 : (m - 1); r1 = m; v0 = 0.25f; v1 = 0.75f; }
    else              { r0 = m; r1 = (m + 1 > 63) ? 63 : (m + 1); v0 = 0.75f; v1 = 0.25f; }

    int ca = (2 * wq - 1 < 0) ? 0 : (2 * wq - 1);
    int cbx = 2 * wq;
    int cc = 2 * wq + 1;
    int cd = (2 * wq + 2 > 63) ? 63 : (2 * wq + 2);

    const ushort* ra = yp + r0 * WsC;
    const ushort* rb = yp + r1 * WsC;
    float a0 = bf2f(ra[ca]), b0 = bf2f(ra[cbx]), e0 = bf2f(ra[cc]), d0 = bf2f(ra[cd]);
    float a1 = bf2f(rb[ca]), b1 = bf2f(rb[cbx]), e1 = bf2f(rb[cc]), d1 = bf2f(rb[cd]);

    float h00 = 0.25f * a0 + 0.75f * b0;
    float h01 = 0.75f * b0 + 0.25f * e0;
    float h02 = 0.25f * b0 + 0.75f * e0;
    float h03 = 0.75f * e0 + 0.25f * d0;
    float h10 = 0.25f * a1 + 0.75f * b1;
    float h11 = 0.75f * b1 + 0.25f * e1;
    float h12 = 0.25f * b1 + 0.75f * e1;
    float h13 = 0.75f * e1 + 0.25f * d1;

    float4 o;
    o.x = v0 * h00 + v1 * h10;
    o.y = v0 * h01 + v1 * h11;
    o.z = v0 * h02 + v1 * h12;
    o.w = v0 * h03 + v1 * h13;

    *(float4*)(out + ((size_t)tb * Cn + c) * (Hn * Wn) + (size_t)h * Wn + 4 * wq) = o;
}

// ---------------------------------------------------------------------------
extern "C" void kernel_launch(void* const* d_in, const int* in_sizes, int n_in,
                              void* d_out, int out_size, void* d_ws, size_t ws_size,
                              hipStream_t stream) {
    const float* x = (const float*)d_in[0];
    const float* w = (const float*)d_in[1];
    float* out = (float*)d_out;

    ushort* y   = (ushort*)d_ws;                                  // 16,777,216 B
    ushort* whi = (ushort*)((uint8_t*)d_ws + (size_t)16777216);   // 32,768 B
    ushort* wlo = (ushort*)((uint8_t*)d_ws + (size_t)16809984);   // 32,768 B

    wprep_kernel<<<64, 256, 0, stream>>>(w, whi, wlo);
    fused_lif_conv<<<1024, 512, 0, stream>>>(x, whi, wlo, y);
    upsample_kernel<<<32768, 256, 0, stream>>>(y, out);
}

// Round 5
// 111.124 us; speedup vs baseline: 1.0004x; 1.0004x over previous
//
#include <hip/hip_runtime.h>
#include <stdint.h>

constexpr int Bn = 8, Cn = 64, Hn = 128, Wn = 128;
constexpr int HsC = 64, WsC = 64;
constexpr int Kn = 256;                 // C * r^2
constexpr int PX = HsC * WsC;           // 4096 pixels per (t,b) plane
constexpr float DECAYF = 0.25f;

typedef __attribute__((ext_vector_type(8))) short short8v;
typedef __attribute__((ext_vector_type(4))) float f32x4;

static __device__ __forceinline__ ushort f2bf_rn(float f) {
    uint32_t u = __float_as_uint(f);
    uint32_t r = (u + 0x7FFFu + ((u >> 16) & 1u)) >> 16;
    return (ushort)r;
}
static __device__ __forceinline__ float bf2f(ushort u) {
    return __uint_as_float(((uint32_t)u) << 16);
}

// u8 spikes (0..4) -> 8 bf16 via v_perm byte-LUT (exact). Verified.
static __device__ __forceinline__ short8v unpack8(uint32_t s0, uint32_t s1) {
    uint32_t lo0 = __builtin_amdgcn_perm(0x00000080u, 0x40008000u, s0);
    uint32_t hi0 = __builtin_amdgcn_perm(0x00000040u, 0x40403F00u, s0);
    uint32_t lo1 = __builtin_amdgcn_perm(0x00000080u, 0x40008000u, s1);
    uint32_t hi1 = __builtin_amdgcn_perm(0x00000040u, 0x40403F00u, s1);
    union { uint32_t u[4]; short8v s; } r;
    r.u[0] = __builtin_amdgcn_perm(hi0, lo0, 0x05010400u);
    r.u[1] = __builtin_amdgcn_perm(hi0, lo0, 0x07030602u);
    r.u[2] = __builtin_amdgcn_perm(hi1, lo1, 0x05010400u);
    r.u[3] = __builtin_amdgcn_perm(hi1, lo1, 0x07030602u);
    return r.s;
}

// ---------------------------------------------------------------------------
// Kernel 0: weight prep — fold /4 dequant, split into bf16 hi + lo
// ---------------------------------------------------------------------------
__global__ __launch_bounds__(256) void wprep_kernel(const float* __restrict__ w,
                                                    ushort* __restrict__ wh,
                                                    ushort* __restrict__ wl) {
    int i = blockIdx.x * 256 + threadIdx.x;     // 16384 total
    float wq = w[i] * 0.25f;
    ushort h = f2bf_rn(wq);
    float hf = bf2f(h);
    wh[i] = h;
    wl[i] = f2bf_rn(wq - hf);
}

// ---------------------------------------------------------------------------
// Fused LIF + 1x1 conv (low res; conv commutes with bilinear upsample).
// Block = 512 threads, owns (b, hs row, ws half): 32 px x 64 input c.
// ALL x loaded up front; sched_barrier(0) pins the 32-load burst so the
// compiler cannot sink loads to their uses (round-4 failure: VGPR=36 proved
// it had serialized them). Then LIF in regs, 4 spike panels in LDS, one
// drain barrier, 4 MFMA phases.
// ---------------------------------------------------------------------------
__global__ __launch_bounds__(512) void fused_lif_conv(const float* __restrict__ x,
                                                      const ushort* __restrict__ wh,
                                                      const ushort* __restrict__ wl,
                                                      ushort* __restrict__ y) {
    __shared__ __align__(16) uint8_t sp_lds[4][32 * 256];   // 32 KB
    __shared__ __align__(8)  uint8_t y_lds[2][32 * 128];    // 8 KB

    const int tid  = threadIdx.x;
    const int pxl  = tid & 31;          // local pixel (ws within half)
    const int cg   = tid >> 5;          // 0..15, channels cg*4..cg*4+3
    const int lane = tid & 63;
    const int wid  = tid >> 6;          // 0..7
    const int l15  = lane & 15;
    const int g    = lane >> 4;
    const int wc   = wid & 3;           // c_out tile (16 c)
    const int wp   = wid >> 2;          // px tile (16 px)

    const int bid  = blockIdx.x;        // 1024 = 8 b x 64 hs x 2 half
    const int half = bid & 1;
    const int hs   = (bid >> 1) & 63;
    const int b    = bid >> 7;

    const int ws_abs = half * 32 + pxl;
    const int c0 = cg * 4;

    const size_t tstr = (size_t)Bn * Cn * Hn * Wn;
    const float* xb = x + ((size_t)b * Cn + c0) * (Hn * Wn) + (2 * hs) * Wn + 2 * ws_abs;

    // ---- load ALL x for this thread's site: 32 independent dwordx2 ----
    float2 xr0[4][4], xr1[4][4];        // [t][ci]
    #pragma unroll
    for (int t = 0; t < 4; ++t) {
        #pragma unroll
        for (int ci = 0; ci < 4; ++ci) {
            const float* xp = xb + (size_t)t * tstr + ci * (Hn * Wn);
            xr0[t][ci] = *(const float2*)xp;
            xr1[t][ci] = *(const float2*)(xp + Wn);
        }
    }
    // Pin the load burst: nothing may be scheduled across this point, so all
    // 32 global_load_dwordx2 are issued back-to-back and stay in flight.
    __builtin_amdgcn_sched_barrier(0);

    // ---- LIF: 16 sequential steps, fully register-resident ----
    uint32_t pk[4][4];                  // [t][ci]
    #pragma unroll
    for (int ci = 0; ci < 4; ++ci) {
        float m = 0.f, s = 0.f, sv;
        #pragma unroll
        for (int t = 0; t < 4; ++t) {
            uint32_t p;
            m = (m - s) * DECAYF + xr0[t][ci].x;
            sv = rintf(fminf(fmaxf(m, 0.f), 4.f)); s = sv * 0.25f; p = (uint32_t)(int)sv;
            m = (m - s) * DECAYF + xr0[t][ci].y;
            sv = rintf(fminf(fmaxf(m, 0.f), 4.f)); s = sv * 0.25f; p |= ((uint32_t)(int)sv) << 8;
            m = (m - s) * DECAYF + xr1[t][ci].x;
            sv = rintf(fminf(fmaxf(m, 0.f), 4.f)); s = sv * 0.25f; p |= ((uint32_t)(int)sv) << 16;
            m = (m - s) * DECAYF + xr1[t][ci].y;
            sv = rintf(fminf(fmaxf(m, 0.f), 4.f)); s = sv * 0.25f; p |= ((uint32_t)(int)sv) << 24;
            pk[t][ci] = p;
        }
    }

    // ---- all 4 spike panels -> LDS (swizzled, 16B granule), one barrier ----
    const int spw = pxl * 256 + ((cg * 16) ^ ((pxl & 15) << 4));
    #pragma unroll
    for (int t = 0; t < 4; ++t)
        *(uint4*)(sp_lds[t] + spw) = make_uint4(pk[t][0], pk[t][1], pk[t][2], pk[t][3]);
    __syncthreads();

    // ---- per-t MFMA + staged writeout ----
    const int bpx  = wp * 16 + l15;                                 // MFMA B pixel
    const int arow = wc * 16 + l15;                                 // MFMA A row (c_out)
    const ushort* whp = wh + arow * Kn;
    const ushort* wlp = wl + arow * Kn;
    const int cb   = wc * 4 + g;                                    // c_out quad idx
    const int ywb  = bpx * 128 + ((cb * 8) ^ ((bpx & 7) << 3));     // y_lds write addr
    const int crow = tid >> 3;          // writeout: c row 0..63
    const int pq   = tid & 7;           // writeout: px quad 0..7

    #pragma unroll
    for (int t = 0; t < 4; ++t) {
        f32x4 acc = {0.f, 0.f, 0.f, 0.f};
        #pragma unroll
        for (int ks = 0; ks < 8; ++ks) {
            int k0 = ks * 32 + g * 8;
            short8v ah = *(const short8v*)(whp + k0);
            short8v al = *(const short8v*)(wlp + k0);
            int rb = bpx * 256 + (k0 ^ ((bpx & 15) << 4));
            uint2 sv2 = *(const uint2*)(sp_lds[t] + rb);
            short8v bf = unpack8(sv2.x, sv2.y);
            acc = __builtin_amdgcn_mfma_f32_16x16x32_bf16(ah, bf, acc, 0, 0, 0);
            acc = __builtin_amdgcn_mfma_f32_16x16x32_bf16(al, bf, acc, 0, 0, 0);
        }

        // epilogue: acc -> y_lds[t&1] [px][c]  (C/D: col=l15=px, row=g*4+r=c)
        uint32_t lo = (uint32_t)f2bf_rn(acc[0]) | ((uint32_t)f2bf_rn(acc[1]) << 16);
        uint32_t hi = (uint32_t)f2bf_rn(acc[2]) | ((uint32_t)f2bf_rn(acc[3]) << 16);
        *(uint2*)(y_lds[t & 1] + ywb) = make_uint2(lo, hi);
        __syncthreads();

        // coalesced y writeout: thread = (crow, pq) -> 4 px bf16
        ushort v[4];
        #pragma unroll
        for (int j = 0; j < 4; ++j) {
            int pxj = pq * 4 + j;
            int addr = pxj * 128 + (((crow >> 2) * 8) ^ ((pxj & 7) << 3)) + (crow & 3) * 2;
            v[j] = *(const ushort*)(y_lds[t & 1] + addr);
        }
        uint2 o = make_uint2((uint32_t)v[0] | ((uint32_t)v[1] << 16),
                             (uint32_t)v[2] | ((uint32_t)v[3] << 16));
        ushort* yg = y + ((size_t)(t * Bn + b) * Cn + crow) * PX + hs * 64 + half * 32 + pq * 4;
        *(uint2*)yg = o;
        // y_lds is double-buffered; next overwrite of this buffer is ordered
        // behind the next phase's barrier.
    }
}

// ---------------------------------------------------------------------------
// Kernel 3: bilinear 2x upsample from bf16 y, half-pixel centers, edge clamp
// ---------------------------------------------------------------------------
__global__ __launch_bounds__(256) void upsample_kernel(const ushort* __restrict__ y,
                                                       float* __restrict__ out) {
    int gg = blockIdx.x * 256 + threadIdx.x;   // 8388608 threads
    int wq = gg & 31;                // output col quad: w0 = 4*wq
    int h  = (gg >> 5) & 127;
    int rr = gg >> 12;
    int c  = rr & 63;
    int tb = rr >> 6;

    const ushort* yp = y + ((size_t)tb * Cn + c) * PX;

    int m = h >> 1;
    int r0, r1; float v0, v1;
    if ((h & 1) == 0) { r0 = (m - 1 < 0) ? 0 : (m - 1); r1 = m; v0 = 0.25f; v1 = 0.75f; }
    else              { r0 = m; r1 = (m + 1 > 63) ? 63 : (m + 1); v0 = 0.75f; v1 = 0.25f; }

    int ca = (2 * wq - 1 < 0) ? 0 : (2 * wq - 1);
    int cbx = 2 * wq;
    int cc = 2 * wq + 1;
    int cd = (2 * wq + 2 > 63) ? 63 : (2 * wq + 2);

    const ushort* ra = yp + r0 * WsC;
    const ushort* rb = yp + r1 * WsC;
    float a0 = bf2f(ra[ca]), b0 = bf2f(ra[cbx]), e0 = bf2f(ra[cc]), d0 = bf2f(ra[cd]);
    float a1 = bf2f(rb[ca]), b1 = bf2f(rb[cbx]), e1 = bf2f(rb[cc]), d1 = bf2f(rb[cd]);

    float h00 = 0.25f * a0 + 0.75f * b0;
    float h01 = 0.75f * b0 + 0.25f * e0;
    float h02 = 0.25f * b0 + 0.75f * e0;
    float h03 = 0.75f * e0 + 0.25f * d0;
    float h10 = 0.25f * a1 + 0.75f * b1;
    float h11 = 0.75f * b1 + 0.25f * e1;
    float h12 = 0.25f * b1 + 0.75f * e1;
    float h13 = 0.75f * e1 + 0.25f * d1;

    float4 o;
    o.x = v0 * h00 + v1 * h10;
    o.y = v0 * h01 + v1 * h11;
    o.z = v0 * h02 + v1 * h12;
    o.w = v0 * h03 + v1 * h13;

    *(float4*)(out + ((size_t)tb * Cn + c) * (Hn * Wn) + (size_t)h * Wn + 4 * wq) = o;
}

// ---------------------------------------------------------------------------
extern "C" void kernel_launch(void* const* d_in, const int* in_sizes, int n_in,
                              void* d_out, int out_size, void* d_ws, size_t ws_size,
                              hipStream_t stream) {
    const float* x = (const float*)d_in[0];
    const float* w = (const float*)d_in[1];
    float* out = (float*)d_out;

    ushort* y   = (ushort*)d_ws;                                  // 16,777,216 B
    ushort* whi = (ushort*)((uint8_t*)d_ws + (size_t)16777216);   // 32,768 B
    ushort* wlo = (ushort*)((uint8_t*)d_ws + (size_t)16809984);   // 32,768 B

    wprep_kernel<<<64, 256, 0, stream>>>(w, whi, wlo);
    fused_lif_conv<<<1024, 512, 0, stream>>>(x, whi, wlo, y);
    upsample_kernel<<<32768, 256, 0, stream>>>(y, out);
}

// Round 6
// 65.878 us; speedup vs baseline: 1.6875x; 1.6868x over previous
//
#include <hip/hip_runtime.h>
#include <stdint.h>

constexpr int Bn = 8, Cn = 64, Hn = 128, Wn = 128;
constexpr int HsC = 64, WsC = 64;
constexpr int Kn = 256;                 // C * r^2
constexpr int PX = HsC * WsC;           // 4096 pixels per (t,b) plane
constexpr float DECAYF = 0.25f;

typedef __attribute__((ext_vector_type(8))) short short8v;
typedef __attribute__((ext_vector_type(4))) float f32x4;

#define WAITV(N) asm volatile("s_waitcnt vmcnt(" #N ")" ::: "memory")
#define WAITL0() asm volatile("s_waitcnt lgkmcnt(0)" ::: "memory")
#define BAR() __builtin_amdgcn_s_barrier()

static __device__ __forceinline__ ushort f2bf_rn(float f) {
    uint32_t u = __float_as_uint(f);
    uint32_t r = (u + 0x7FFFu + ((u >> 16) & 1u)) >> 16;
    return (ushort)r;
}
static __device__ __forceinline__ float bf2f(ushort u) {
    return __uint_as_float(((uint32_t)u) << 16);
}

// u8 spikes (0..4) -> 8 bf16 via v_perm byte-LUT (exact). Verified.
static __device__ __forceinline__ short8v unpack8(uint32_t s0, uint32_t s1) {
    uint32_t lo0 = __builtin_amdgcn_perm(0x00000080u, 0x40008000u, s0);
    uint32_t hi0 = __builtin_amdgcn_perm(0x00000040u, 0x40403F00u, s0);
    uint32_t lo1 = __builtin_amdgcn_perm(0x00000080u, 0x40008000u, s1);
    uint32_t hi1 = __builtin_amdgcn_perm(0x00000040u, 0x40403F00u, s1);
    union { uint32_t u[4]; short8v s; } r;
    r.u[0] = __builtin_amdgcn_perm(hi0, lo0, 0x05010400u);
    r.u[1] = __builtin_amdgcn_perm(hi0, lo0, 0x07030602u);
    r.u[2] = __builtin_amdgcn_perm(hi1, lo1, 0x05010400u);
    r.u[3] = __builtin_amdgcn_perm(hi1, lo1, 0x07030602u);
    return r.s;
}

// async 16B global -> LDS (no dest VGPRs; queue depth = vmcnt)
static __device__ __forceinline__ void gload_lds16(const void* gsrc, void* ldst) {
    __builtin_amdgcn_global_load_lds((const __attribute__((address_space(1))) uint32_t*)gsrc,
                                     (__attribute__((address_space(3))) uint32_t*)ldst, 16, 0, 0);
}

// ---------------------------------------------------------------------------
// Kernel 0: weight prep — fold /4, split bf16 hi+lo, PERMUTED for the conv's
// register preload: dst[((wc*8+ks)*64 + lane)*8 + j] =
//   wq(row = wc*16 + (lane&15), k = ks*32 + (lane>>4)*8 + j)
// so the conv wave reads 1KB fully-coalesced per (wc,ks).
// ---------------------------------------------------------------------------
__global__ __launch_bounds__(256) void wprep_kernel(const float* __restrict__ w,
                                                    ushort* __restrict__ wh,
                                                    ushort* __restrict__ wl) {
    int gid = blockIdx.x * 256 + threadIdx.x;   // 2048 total
    int lane = gid & 63, ks = (gid >> 6) & 7, wc = gid >> 9;
    int row = wc * 16 + (lane & 15);
    int kb = ks * 32 + (lane >> 4) * 8;
    #pragma unroll
    for (int j = 0; j < 8; ++j) {
        float wq = w[row * 256 + kb + j] * 0.25f;
        ushort h = f2bf_rn(wq);
        wh[gid * 8 + j] = h;
        wl[gid * 8 + j] = f2bf_rn(wq - bf2f(h));
    }
}

// ---------------------------------------------------------------------------
// stage one t's x tile (64c x 2rows x 64cols = 32KB) into LDS buffer.
// chunk q = c*2+row (256B each); wave wid handles groups {wid, 8+wid, 16+wid,
// 24+wid}, 4 chunks (1KB) per global_load_lds. Linear LDS dest.
// ---------------------------------------------------------------------------
static __device__ __forceinline__ void stage_tile(const float* __restrict__ x,
                                                  uint8_t* xb, int t, int b,
                                                  int hs, int half, int wid, int lane) {
    const size_t tstr = (size_t)Bn * Cn * Hn * Wn;
    #pragma unroll
    for (int i = 0; i < 4; ++i) {
        int grp = i * 8 + wid;
        int q = 4 * grp + (lane >> 4);
        int cch = q >> 1, row = q & 1;
        const float* gsrc = x + (size_t)t * tstr + ((size_t)b * Cn + cch) * (Hn * Wn)
                            + (2 * hs + row) * Wn + half * 64 + (lane & 15) * 4;
        gload_lds16(gsrc, xb + (size_t)grp * 1024);
    }
}

// ---------------------------------------------------------------------------
// Fused LIF + 1x1 conv (low res; conv commutes with bilinear upsample).
// Raw s_barrier + counted vmcnt (never 0 mid-loop). Weights in registers.
// ---------------------------------------------------------------------------
__global__ __launch_bounds__(512, 4) void fused_lif_conv(const float* __restrict__ x,
                                                         const ushort* __restrict__ wh,
                                                         const ushort* __restrict__ wl,
                                                         ushort* __restrict__ y) {
    __shared__ __align__(16) uint8_t xbuf[2][32 * 1024];  // 64 KB x double-buffer
    __shared__ __align__(16) uint8_t sp_lds[32 * 256];    // 8 KB spikes [px][k]
    __shared__ __align__(8)  uint8_t y_lds[32 * 128];     // 4 KB [px][c] bf16

    const int tid  = threadIdx.x;
    const int pxl  = tid & 31;          // local pixel
    const int cg   = tid >> 5;          // 0..15 -> channels cg*4..cg*4+3
    const int lane = tid & 63;
    const int wid  = tid >> 6;          // 0..7
    const int l15  = lane & 15;
    const int g    = lane >> 4;
    const int wc   = wid & 3;           // c_out tile (16 c)
    const int wp   = wid >> 2;          // px tile (16 px)

    const int bid  = blockIdx.x;        // 1024 = 8 b x 64 hs x 2 half
    const int half = bid & 1;
    const int hs   = (bid >> 1) & 63;
    const int b    = bid >> 7;
    const int c0   = cg * 4;

    // ---- prologue: S0, weights (16 coalesced loads -> 64 VGPR), S1 ----
    stage_tile(x, xbuf[0], 0, b, hs, half, wid, lane);    // S0 (4 ops/wave)
    __builtin_amdgcn_sched_barrier(0);
    short8v wrh[8], wrl[8];
    {
        const short8v* ph = (const short8v*)wh + (size_t)(wc * 8) * 64 + lane;
        const short8v* pl = (const short8v*)wl + (size_t)(wc * 8) * 64 + lane;
        #pragma unroll
        for (int ks = 0; ks < 8; ++ks) { wrh[ks] = ph[ks * 64]; wrl[ks] = pl[ks * 64]; }
    }
    __builtin_amdgcn_sched_barrier(0);
    stage_tile(x, xbuf[1], 1, b, hs, half, wid, lane);    // S1

    float mem[4] = {0.f, 0.f, 0.f, 0.f}, spk[4] = {0.f, 0.f, 0.f, 0.f};

    const int spw  = pxl * 256 + ((cg * 16) ^ ((pxl & 15) << 4));  // spike write
    const int bpx  = wp * 16 + l15;                                 // MFMA B pixel
    const int cb   = wc * 4 + g;                                    // c_out quad
    const int ywb  = bpx * 128 + ((cb * 8) ^ ((bpx & 7) << 3));     // y_lds write
    const int crow = tid >> 3;          // writeout c row
    const int pq   = tid & 7;           // writeout px quad

    #pragma unroll
    for (int t = 0; t < 4; ++t) {
        // ---- bar A: wait this t's stage group (counted; y-stores included) ----
        // vmem program order: S0(4) W(16) S1(4) | S2(4) yst0(1) | S3(4) yst1(1) | yst2(1)
        if (t == 0)      WAITV(20);   // retire S0
        else if (t == 1) WAITV(5);    // retire ..S1  (newer: S2x4 + yst0)
        else if (t == 2) WAITV(6);    // retire ..S2  (newer: yst0, S3x4, yst1)
        else             WAITV(2);    // retire ..S3  (newer: yst1, yst2)
        BAR();
        __builtin_amdgcn_sched_barrier(0);

        // ---- LIF t from LDS (ds_read_b64 pairs), p order = r0.x r0.y r1.x r1.y ----
        const uint8_t* xb = xbuf[t & 1];
        uint32_t pk[4];
        #pragma unroll
        for (int ci = 0; ci < 4; ++ci) {
            int qoff = ((c0 + ci) * 2) * 256 + pxl * 8;
            float2 r0v = *(const float2*)(xb + qoff);
            float2 r1v = *(const float2*)(xb + qoff + 256);
            float m = mem[ci], s = spk[ci], sv;
            uint32_t p;
            m = (m - s) * DECAYF + r0v.x;
            sv = rintf(fminf(fmaxf(m, 0.f), 4.f)); s = sv * 0.25f; p = (uint32_t)(int)sv;
            m = (m - s) * DECAYF + r0v.y;
            sv = rintf(fminf(fmaxf(m, 0.f), 4.f)); s = sv * 0.25f; p |= ((uint32_t)(int)sv) << 8;
            m = (m - s) * DECAYF + r1v.x;
            sv = rintf(fminf(fmaxf(m, 0.f), 4.f)); s = sv * 0.25f; p |= ((uint32_t)(int)sv) << 16;
            m = (m - s) * DECAYF + r1v.y;
            sv = rintf(fminf(fmaxf(m, 0.f), 4.f)); s = sv * 0.25f; p |= ((uint32_t)(int)sv) << 24;
            mem[ci] = m; spk[ci] = s; pk[ci] = p;
        }
        *(uint4*)(sp_lds + spw) = make_uint4(pk[0], pk[1], pk[2], pk[3]);
        WAITL0();
        BAR();      // bar B: spikes visible; xbuf[t&1] fully consumed

        // ---- prefetch t+2 into the buffer just freed (flies across MFMA) ----
        if (t < 2) stage_tile(x, xbuf[t & 1], t + 2, b, hs, half, wid, lane);

        // ---- MFMA: 16 x 16x16x32 bf16, zero VMEM in this phase ----
        f32x4 acc = {0.f, 0.f, 0.f, 0.f};
        #pragma unroll
        for (int ks = 0; ks < 8; ++ks) {
            int k0 = ks * 32 + g * 8;
            int rb = bpx * 256 + (k0 ^ ((bpx & 15) << 4));
            uint2 sv2 = *(const uint2*)(sp_lds + rb);
            short8v bfv = unpack8(sv2.x, sv2.y);
            acc = __builtin_amdgcn_mfma_f32_16x16x32_bf16(wrh[ks], bfv, acc, 0, 0, 0);
            acc = __builtin_amdgcn_mfma_f32_16x16x32_bf16(wrl[ks], bfv, acc, 0, 0, 0);
        }

        // ---- epilogue: acc -> y_lds (C/D: col=l15=px, row=g*4+r=c) ----
        uint32_t lo = (uint32_t)f2bf_rn(acc[0]) | ((uint32_t)f2bf_rn(acc[1]) << 16);
        uint32_t hi = (uint32_t)f2bf_rn(acc[2]) | ((uint32_t)f2bf_rn(acc[3]) << 16);
        *(uint2*)(y_lds + ywb) = make_uint2(lo, hi);
        WAITL0();
        BAR();      // bar C: y_lds visible

        ushort v[4];
        #pragma unroll
        for (int j = 0; j < 4; ++j) {
            int pxj = pq * 4 + j;
            int addr = pxj * 128 + (((crow >> 2) * 8) ^ ((pxj & 7) << 3)) + (crow & 3) * 2;
            v[j] = *(const ushort*)(y_lds + addr);
        }
        uint2 o = make_uint2((uint32_t)v[0] | ((uint32_t)v[1] << 16),
                             (uint32_t)v[2] | ((uint32_t)v[3] << 16));
        ushort* yg = y + ((size_t)(t * Bn + b) * Cn + crow) * PX + hs * 64 + half * 32 + pq * 4;
        *(uint2*)yg = o;
        // next iteration's bar A orders y_lds/sp_lds reuse
    }
}

// ---------------------------------------------------------------------------
// Kernel 3: bilinear 2x upsample from bf16 y, half-pixel centers, edge clamp
// ---------------------------------------------------------------------------
__global__ __launch_bounds__(256) void upsample_kernel(const ushort* __restrict__ y,
                                                       float* __restrict__ out) {
    int gg = blockIdx.x * 256 + threadIdx.x;   // 8388608 threads
    int wq = gg & 31;                // output col quad: w0 = 4*wq
    int h  = (gg >> 5) & 127;
    int rr = gg >> 12;
    int c  = rr & 63;
    int tb = rr >> 6;

    const ushort* yp = y + ((size_t)tb * Cn + c) * PX;

    int m = h >> 1;
    int r0, r1; float v0, v1;
    if ((h & 1) == 0) { r0 = (m - 1 < 0) ? 0 : (m - 1); r1 = m; v0 = 0.25f; v1 = 0.75f; }
    else              { r0 = m; r1 = (m + 1 > 63) ? 63 : (m + 1); v0 = 0.75f; v1 = 0.25f; }

    int ca = (2 * wq - 1 < 0) ? 0 : (2 * wq - 1);
    int cbx = 2 * wq;
    int cc = 2 * wq + 1;
    int cd = (2 * wq + 2 > 63) ? 63 : (2 * wq + 2);

    const ushort* ra = yp + r0 * WsC;
    const ushort* rb = yp + r1 * WsC;
    float a0 = bf2f(ra[ca]), b0 = bf2f(ra[cbx]), e0 = bf2f(ra[cc]), d0 = bf2f(ra[cd]);
    float a1 = bf2f(rb[ca]), b1 = bf2f(rb[cbx]), e1 = bf2f(rb[cc]), d1 = bf2f(rb[cd]);

    float h00 = 0.25f * a0 + 0.75f * b0;
    float h01 = 0.75f * b0 + 0.25f * e0;
    float h02 = 0.25f * b0 + 0.75f * e0;
    float h03 = 0.75f * e0 + 0.25f * d0;
    float h10 = 0.25f * a1 + 0.75f * b1;
    float h11 = 0.75f * b1 + 0.25f * e1;
    float h12 = 0.25f * b1 + 0.75f * e1;
    float h13 = 0.75f * e1 + 0.25f * d1;

    float4 o;
    o.x = v0 * h00 + v1 * h10;
    o.y = v0 * h01 + v1 * h11;
    o.z = v0 * h02 + v1 * h12;
    o.w = v0 * h03 + v1 * h13;

    *(float4*)(out + ((size_t)tb * Cn + c) * (Hn * Wn) + (size_t)h * Wn + 4 * wq) = o;
}

// ---------------------------------------------------------------------------
extern "C" void kernel_launch(void* const* d_in, const int* in_sizes, int n_in,
                              void* d_out, int out_size, void* d_ws, size_t ws_size,
                              hipStream_t stream) {
    const float* x = (const float*)d_in[0];
    const float* w = (const float*)d_in[1];
    float* out = (float*)d_out;

    ushort* y   = (ushort*)d_ws;                                  // 16,777,216 B
    ushort* whi = (ushort*)((uint8_t*)d_ws + (size_t)16777216);   // 32,768 B
    ushort* wlo = (ushort*)((uint8_t*)d_ws + (size_t)16809984);   // 32,768 B

    wprep_kernel<<<8, 256, 0, stream>>>(w, whi, wlo);
    fused_lif_conv<<<1024, 512, 0, stream>>>(x, whi, wlo, y);
    upsample_kernel<<<32768, 256, 0, stream>>>(y, out);
}